// Round 9
// baseline (59.942 us; speedup 1.0000x reference)
//
#include <hip/hip_runtime.h>
#include <hip/hip_bf16.h>

// y = x @ W^T + b ; x:(16,8192,256) f32, W:(256,256) f32, b:(256,) f32, out f32
// M=131072, N=256, K=256. Memory-bound.
// R9 = R8 with ONE change: C-stores via inline asm `global_store_dword ... sc0 sc1 nt`
//      (full streaming/no-allocate policy; __builtin_nontemporal_store sets nt only).
// Theory: x(134MB)+out(134MB) > 256MB L3 -> out evicts half of x every replay
//      (FETCH pinned at 68MB = x/2). If out stops allocating in L3, x becomes
//      L3-resident -> HBM/replay ~= writes only (134MB) -> dur ~42-50us.
// Safety: cache bits are hints; untracked asm stores make compiler vmcnt waits
//      MORE conservative (FIFO), and R8 proved drains cost ~0 here.
// History: R2 grid-tail confound; R3 transposed loads = VMEM death; R4 restructure
//      hurt; R5 nt +3us; R7 partial-line stores = write amp; R8 = R5 (drain null).

typedef __attribute__((ext_vector_type(8))) short bf16x8;
typedef __attribute__((ext_vector_type(16))) float f32x16;

__device__ __forceinline__ short f2bf(float f) {
    __hip_bfloat16 h = __float2bfloat16(f);   // RTNE
    return *reinterpret_cast<short*>(&h);
}

__device__ __forceinline__ void store_stream(float* p, float v) {
    // full streaming store: system-scope, no-allocate, non-temporal
    asm volatile("global_store_dword %0, %1, off sc0 sc1 nt" :: "v"(p), "v"(v));
}

#define BM   32
#define LDSK 264   // 256 + 8 pad: 528B row stride -> conflict-free b128 frag reads

__global__ __launch_bounds__(512, 4)
void rac_linear_kernel(const float* __restrict__ x,
                       const float* __restrict__ w,
                       const float* __restrict__ bias,
                       float* __restrict__ out,
                       int tiles_per_block)
{
    __shared__ short lds[2][BM * LDSK];   // 2 x 16.5 KB

    const int tid  = threadIdx.x;
    const int lane = tid & 63;
    const int wv   = tid >> 6;        // 0..7: N-wave, owns cols [wv*32, wv*32+32)
    const int l31  = lane & 31;
    const int lh   = lane >> 5;       // 0/1: k-half of the fragment

    // ---- B prologue: W[n][k] -> per-wave bf16 register fragments ----
    // B frag layout (32x32x16): col = lane&31 (n), k = (lane>>5)*8 + j
    bf16x8 bfrag[16];
    {
        const int   wrow = wv * 32 + l31;                 // n index
        const float* wb  = w + (size_t)wrow * 256 + lh * 8;
        #pragma unroll
        for (int ks = 0; ks < 16; ++ks) {
            const float4 lo = *reinterpret_cast<const float4*>(wb + ks * 16);
            const float4 hi = *reinterpret_cast<const float4*>(wb + ks * 16 + 4);
            bf16x8 b;
            b[0]=f2bf(lo.x); b[1]=f2bf(lo.y); b[2]=f2bf(lo.z); b[3]=f2bf(lo.w);
            b[4]=f2bf(hi.x); b[5]=f2bf(hi.y); b[6]=f2bf(hi.z); b[7]=f2bf(hi.w);
            bfrag[ks] = b;
        }
    }
    const float bval = bias[wv * 32 + l31];

    const int t0 = blockIdx.x * tiles_per_block;

    float4 v[4];   // staging registers (one BM x 256 f32 tile = 64 B/thread)

    // prologue: load + stage tile t0 into buf 0
    {
        const float4* src = reinterpret_cast<const float4*>(x + (size_t)t0 * (BM * 256));
        #pragma unroll
        for (int i = 0; i < 4; ++i) v[i] = src[i * 512 + tid];   // fully coalesced
        #pragma unroll
        for (int i = 0; i < 4; ++i) {
            const int row = i * 8 + (tid >> 6);      // elem = i*2048 + tid*4
            const int k   = (tid & 63) * 4;
            short4 s;
            s.x=f2bf(v[i].x); s.y=f2bf(v[i].y); s.z=f2bf(v[i].z); s.w=f2bf(v[i].w);
            *reinterpret_cast<short4*>(&lds[0][row * LDSK + k]) = s;
        }
    }

    for (int t = 0; t < tiles_per_block; ++t) {
        const int buf  = t & 1;
        const int tile = t0 + t;

        // LDS-visibility barrier (R8: drain-vs-not is perf-neutral here)
        asm volatile("s_waitcnt lgkmcnt(0)\n\ts_barrier" ::: "memory");

        // issue next tile's global loads early (latency hidden under compute)
        if (t + 1 < tiles_per_block) {
            const float4* src =
                reinterpret_cast<const float4*>(x + (size_t)(tile + 1) * (BM * 256));
            #pragma unroll
            for (int i = 0; i < 4; ++i) v[i] = src[i * 512 + tid];
        }

        // ---- compute: 16 K-steps of mfma_f32_32x32x16_bf16 ----
        f32x16 acc;
        #pragma unroll
        for (int r = 0; r < 16; ++r) acc[r] = bval;

        // A frag layout: row = lane&31 (m), k = (lane>>5)*8 + j
        const short* abase = &lds[buf][l31 * LDSK + lh * 8];
        #pragma unroll
        for (int ks = 0; ks < 16; ++ks) {
            bf16x8 a = *reinterpret_cast<const bf16x8*>(abase + ks * 16);
            acc = __builtin_amdgcn_mfma_f32_32x32x16_bf16(a, bfrag[ks], acc, 0, 0, 0);
        }

        // ---- epilogue: C layout col=lane&31, row=(r&3)+8*(r>>2)+4*(lane>>5) ----
        // 32 lanes sweep one output row -> full 128B line coverage per instr
        // (R7 lesson). STREAMING stores: sc0 sc1 nt = no L3 allocation.
        {
            float* ob = out + (size_t)tile * (BM * 256) + wv * 32 + l31;
            const int rhi = lh * 4;
            #pragma unroll
            for (int r = 0; r < 16; ++r) {
                const int row = (r & 3) + 8 * (r >> 2) + rhi;
                store_stream(&ob[(size_t)row * 256], acc[r]);
            }
        }

        // stage next tile into the other buffer (safe: all waves past barrier)
        if (t + 1 < tiles_per_block) {
            #pragma unroll
            for (int i = 0; i < 4; ++i) {
                const int row = i * 8 + (tid >> 6);
                const int k   = (tid & 63) * 4;
                short4 s;
                s.x=f2bf(v[i].x); s.y=f2bf(v[i].y); s.z=f2bf(v[i].z); s.w=f2bf(v[i].w);
                *reinterpret_cast<short4*>(&lds[buf ^ 1][row * LDSK + k]) = s;
            }
        }
    }
}

extern "C" void kernel_launch(void* const* d_in, const int* in_sizes, int n_in,
                              void* d_out, int out_size, void* d_ws, size_t ws_size,
                              hipStream_t stream)
{
    const float* x    = (const float*)d_in[0];
    const float* w    = (const float*)d_in[1];
    const float* bias = (const float*)d_in[2];
    float* out        = (float*)d_out;

    const int M      = in_sizes[0] / 256;   // 131072 rows
    const int ntiles = M / BM;              // 4096
    const int grid   = 512;                 // 2 blocks/CU
    const int tpb    = ntiles / grid;       // 8 tiles per block

    rac_linear_kernel<<<grid, 512, 0, stream>>>(x, w, bias, out, tpb);
}